// Round 12
// baseline (564.515 us; speedup 1.0000x reference)
//
#include <hip/hip_runtime.h>
#include <hip/hip_bf16.h>

#define HF 64
#define EPS 1e-5f

#define BSH 9                    // bucket shift: 512 nodes / bucket
#define BKN (1 << BSH)           // 512 nodes per bucket
#define NBUCK_MAX 256            // >= ceil(N / BKN)
#define PB_T 256                 // passB threads
#define PB_EPT 32                // edges per thread
#define PB_TILE (PB_T * PB_EPT)  // 8192 edges per block

#define LGRID 1536               // k_layer grid; grid-stride over nodes

typedef __hip_bfloat16 bf16;

__device__ __forceinline__ unsigned char f32_to_fp8(float v) {
    int p = __builtin_amdgcn_cvt_pk_fp8_f32(v, v, 0, false);
    return (unsigned char)(p & 0xff);
}

__device__ __forceinline__ float bcast_lane(float v, int k) {
    return __uint_as_float(__builtin_amdgcn_readlane(__float_as_uint(v), k));
}

// ---- bucket histogram: LDS per-block, one global atomic per (block,bucket) ----
__global__ __launch_bounds__(PB_T) void k_bhist(const int* __restrict__ dst,
                                                int* __restrict__ bcnt, int E, int B) {
    __shared__ int bh[NBUCK_MAX];
    int t = threadIdx.x;
    for (int b = t; b < B; b += PB_T) bh[b] = 0;
    __syncthreads();
    int tile0 = blockIdx.x * PB_TILE;
#pragma unroll
    for (int k = 0; k < PB_EPT; ++k) {
        int e = tile0 + k * PB_T + t;
        if (e < E) atomicAdd(&bh[dst[e] >> BSH], 1);
    }
    __syncthreads();
    for (int b = t; b < B; b += PB_T) {
        int c = bh[b];
        if (c) atomicAdd(&bcnt[b], c);
    }
}

// ---- bucket scan: bbase2 = excl scan(bcnt); bcur = bbase2; base[N] = E ----
__global__ void k_bscan(const int* __restrict__ bcnt, int* __restrict__ bbase2,
                        int* __restrict__ bcur, int* __restrict__ base, int B, int N, int E) {
    if (threadIdx.x == 0 && blockIdx.x == 0) {
        int acc = 0;
        for (int i = 0; i < B; ++i) { bbase2[i] = acc; bcur[i] = acc; acc += bcnt[i]; }
        bbase2[B] = acc;   // == E
        base[N] = E;
    }
}

// ---- pass B: block-tiled binning; reserve per-(block,bucket) RUNS, write block-private ----
__global__ __launch_bounds__(PB_T) void k_passB(
    const int* __restrict__ src, const int* __restrict__ dst,
    int* __restrict__ bcur, int* __restrict__ stage, int E, int B) {
    __shared__ int scnt[NBUCK_MAX];
    __shared__ int sgoff[NBUCK_MAX];
    int t = threadIdx.x;
    int tile0 = blockIdx.x * PB_TILE;

    for (int b = t; b < B; b += PB_T) scnt[b] = 0;
    __syncthreads();

    int rec[PB_EPT];
    int bkt[PB_EPT];
#pragma unroll
    for (int k = 0; k < PB_EPT; ++k) {
        int e = tile0 + k * PB_T + t;
        bkt[k] = -1;
        if (e < E) {
            int d = dst[e];
            int s = src[e];
            int b = d >> BSH;
            bkt[k] = b;
            rec[k] = s | ((d & (BKN - 1)) << 17);
            atomicAdd(&scnt[b], 1);
        }
    }
    __syncthreads();

    for (int b = t; b < B; b += PB_T) {
        int c = scnt[b];
        sgoff[b] = c ? atomicAdd(&bcur[b], c) : 0;
        scnt[b] = 0;
    }
    __syncthreads();

#pragma unroll
    for (int k = 0; k < PB_EPT; ++k) {
        if (bkt[k] >= 0) {
            int loc = atomicAdd(&scnt[bkt[k]], 1);
            stage[sgoff[bkt[k]] + loc] = rec[k];
        }
    }
}

// ---- pass C: per bucket: LDS node-hist -> scan -> base/dinv -> scatter csr ----
__global__ __launch_bounds__(512) void k_passC(const int* __restrict__ stage,
                                               const int* __restrict__ bb2,
                                               int* __restrict__ base,
                                               float* __restrict__ dinv,
                                               int* __restrict__ csr, int N) {
    __shared__ int lcnt[BKN];
    __shared__ int lscan[BKN];
    __shared__ int lcur[BKN];
    int beta = blockIdx.x;
    int n0 = beta * BKN;
    int n1 = n0 + BKN; if (n1 > N) n1 = N;
    int nn = n1 - n0;
    int t = threadIdx.x;       // blockDim == 512 == BKN
    lcnt[t] = 0;
    __syncthreads();
    int rbeg = bb2[beta], rend = bb2[beta + 1];
    for (int i = rbeg + t; i < rend; i += 512)
        atomicAdd(&lcnt[stage[i] >> 17], 1);
    __syncthreads();
    int v = lcnt[t];
    lscan[t] = v;
    __syncthreads();
    for (int off = 1; off < 512; off <<= 1) {
        int val = lscan[t];
        int add = (t >= off) ? lscan[t - off] : 0;
        __syncthreads();
        lscan[t] = val + add;
        __syncthreads();
    }
    int b = rbeg + lscan[t] - v;   // exclusive scan + bucket start
    if (t < nn) {
        base[n0 + t] = b;
        dinv[n0 + t] = rsqrtf((float)v + 1.0f);
    }
    lcur[t] = b;
    __syncthreads();
    for (int i = rbeg + t; i < rend; i += 512) {
        int r = stage[i];
        int pos = atomicAdd(&lcur[r >> 17], 1);
        csr[pos] = r & 0x1ffff;
    }
}

// ---- prescale: xs[n,c] = x[n,c] * dinv[n] ----
__global__ void k_prescale(const float* __restrict__ x, const float* __restrict__ dinv,
                           float* __restrict__ xs, int N5) {
    int i = blockIdx.x * blockDim.x + threadIdx.x;
    if (i < N5) xs[i] = x[i] * dinv[i / 5];
}

// ---- layer 1 fused: W column in VGPRs, readlane matmul, grid-stride over nodes ----
__global__ __launch_bounds__(256, 5) void k_layer1(
    const float* __restrict__ xs, unsigned char* __restrict__ hout,
    const int* __restrict__ csr, const int* __restrict__ basep,
    const float* __restrict__ dinv,
    const float* __restrict__ W1, const float* __restrict__ b,
    const float* __restrict__ g, const float* __restrict__ be,
    const float* __restrict__ rm, const float* __restrict__ rv, int N) {
    int lane = threadIdx.x & 63;
    int wave = threadIdx.x >> 6;
    int stride = gridDim.x * 4;

    // per-lane folded params (lane == output feature f)
    float scale = g[lane] * rsqrtf(rv[lane] + EPS);
    float bias  = (b[lane] - rm[lane]) * scale + be[lane];
    float wcol[5];
#pragma unroll
    for (int k = 0; k < 5; ++k) wcol[k] = W1[k * HF + lane] * scale;

    for (int node = blockIdx.x * 4 + wave; node < N; node += stride) {
        int j   = __builtin_amdgcn_readfirstlane(basep[node]);
        int end = __builtin_amdgcn_readfirstlane(basep[node + 1]);

        float a0 = 0.f, a1 = 0.f, a2 = 0.f, a3 = 0.f;
        if (lane < 5) a0 = xs[node * 5 + lane];   // self term
        for (; j + 8 <= end; j += 8) {
            int s0 = csr[j+0], s1 = csr[j+1], s2 = csr[j+2], s3 = csr[j+3];
            int s4 = csr[j+4], s5 = csr[j+5], s6 = csr[j+6], s7 = csr[j+7];
            if (lane < 5) {
                float v0 = xs[s0 * 5 + lane], v1 = xs[s1 * 5 + lane];
                float v2 = xs[s2 * 5 + lane], v3 = xs[s3 * 5 + lane];
                float v4 = xs[s4 * 5 + lane], v5 = xs[s5 * 5 + lane];
                float v6 = xs[s6 * 5 + lane], v7 = xs[s7 * 5 + lane];
                a0 += v0; a1 += v1; a2 += v2; a3 += v3;
                a0 += v4; a1 += v5; a2 += v6; a3 += v7;
            }
        }
        for (; j < end; ++j) {
            int s = csr[j];
            if (lane < 5) a0 += xs[s * 5 + lane];
        }
        float di = dinv[node];
        float acc = ((a0 + a1) + (a2 + a3)) * di;

        float out = bias;
#pragma unroll
        for (int k = 0; k < 5; ++k) out += bcast_lane(acc, k) * wcol[k];
        out = fmaxf(out, 0.f);
        hout[(size_t)node * HF + lane] = f32_to_fp8(out * di);  // pre-scale for next layer
    }
}

// ---- layers 2/3 fused: fp8 gather, W column in VGPRs, readlane matmul ----
// SCALE_OUT=1: write fp8 hs = h*dinv. SCALE_OUT=0: write fp32 h (feeds pool).
template <int SCALE_OUT>
__global__ __launch_bounds__(256, 5) void k_layer(
    const unsigned char* __restrict__ hs8, void* __restrict__ hout_v,
    const int* __restrict__ csr, const int* __restrict__ basep,
    const float* __restrict__ dinv,
    const float* __restrict__ W, const float* __restrict__ b,
    const float* __restrict__ g, const float* __restrict__ be,
    const float* __restrict__ rm, const float* __restrict__ rv, int N) {
    int lane = threadIdx.x & 63;
    int wave = threadIdx.x >> 6;
    int stride = gridDim.x * 4;

    // per-lane folded params (lane == output feature f); W column f in VGPRs
    float scale = g[lane] * rsqrtf(rv[lane] + EPS);
    float bias  = (b[lane] - rm[lane]) * scale + be[lane];
    float wcol[HF];
#pragma unroll
    for (int k = 0; k < HF; ++k) wcol[k] = W[k * HF + lane] * scale;

    const unsigned char* col = hs8 + lane;   // lane's feature column

    for (int node = blockIdx.x * 4 + wave; node < N; node += stride) {
        int j   = __builtin_amdgcn_readfirstlane(basep[node]);
        int end = __builtin_amdgcn_readfirstlane(basep[node + 1]);

        // self term (already *dinv[src])
        float a0 = __builtin_amdgcn_cvt_f32_fp8((unsigned)col[(size_t)node * HF], 0);
        float a1 = 0.f, a2 = 0.f, a3 = 0.f;

        // 8-wide MLP: 8 adjacent scalar index loads, then 8 independent byte-gathers
        for (; j + 8 <= end; j += 8) {
            int s0 = csr[j+0], s1 = csr[j+1], s2 = csr[j+2], s3 = csr[j+3];
            int s4 = csr[j+4], s5 = csr[j+5], s6 = csr[j+6], s7 = csr[j+7];
            unsigned u0 = col[(size_t)s0 * HF];
            unsigned u1 = col[(size_t)s1 * HF];
            unsigned u2 = col[(size_t)s2 * HF];
            unsigned u3 = col[(size_t)s3 * HF];
            unsigned u4 = col[(size_t)s4 * HF];
            unsigned u5 = col[(size_t)s5 * HF];
            unsigned u6 = col[(size_t)s6 * HF];
            unsigned u7 = col[(size_t)s7 * HF];
            a0 += __builtin_amdgcn_cvt_f32_fp8(u0, 0);
            a1 += __builtin_amdgcn_cvt_f32_fp8(u1, 0);
            a2 += __builtin_amdgcn_cvt_f32_fp8(u2, 0);
            a3 += __builtin_amdgcn_cvt_f32_fp8(u3, 0);
            a0 += __builtin_amdgcn_cvt_f32_fp8(u4, 0);
            a1 += __builtin_amdgcn_cvt_f32_fp8(u5, 0);
            a2 += __builtin_amdgcn_cvt_f32_fp8(u6, 0);
            a3 += __builtin_amdgcn_cvt_f32_fp8(u7, 0);
        }
        for (; j < end; ++j) {
            int s = csr[j];
            a0 += __builtin_amdgcn_cvt_f32_fp8((unsigned)col[(size_t)s * HF], 0);
        }
        float di = dinv[node];
        float acc = ((a0 + a1) + (a2 + a3)) * di;

        // matvec: out[f] = bias + sum_k acc_k * wcol[k]  (readlane broadcast, no LDS)
        float out = bias;
#pragma unroll
        for (int k = 0; k < HF; ++k) out += bcast_lane(acc, k) * wcol[k];
        out = fmaxf(out, 0.f);
        if (SCALE_OUT) {
            ((unsigned char*)hout_v)[(size_t)node * HF + lane] = f32_to_fp8(out * di);
        } else {
            ((float*)hout_v)[(size_t)node * HF + lane] = out;
        }
    }
}

// ---- per-graph mean-pool + FC(64->32) relu + FC(32->2) sigmoid ----
__global__ void k_pool_fc(const float* __restrict__ h, const int* __restrict__ batch,
                          const float* __restrict__ Wf1, const float* __restrict__ bf1,
                          const float* __restrict__ Wf2, const float* __restrict__ bf2,
                          float* __restrict__ out, int N) {
    int g = blockIdx.x;
    int t = threadIdx.x;
    int f = t & 63, q = t >> 6;

    int lo = 0, hi = N;
    while (lo < hi) { int mid = (lo + hi) >> 1; if (batch[mid] < g) lo = mid + 1; else hi = mid; }
    int start = lo;
    hi = N;
    while (lo < hi) { int mid = (lo + hi) >> 1; if (batch[mid] < g + 1) lo = mid + 1; else hi = mid; }
    int end = lo;

    float sum = 0.f;
    for (int n = start + q; n < end; n += 4) sum += h[n * HF + f];

    __shared__ float red[4][HF];
    __shared__ float sp[HF];
    __shared__ float sh[32];
    red[q][f] = sum;
    __syncthreads();
    if (q == 0) {
        float s = red[0][f] + red[1][f] + red[2][f] + red[3][f];
        float cntf = (float)(end - start);
        sp[f] = s / fmaxf(cntf, 1.0f);
    }
    __syncthreads();
    if (t < 32) {
        float a = bf1[t];
#pragma unroll
        for (int k = 0; k < HF; ++k) a += sp[k] * Wf1[k * 32 + t];
        sh[t] = fmaxf(a, 0.f);
    }
    __syncthreads();
    if (t < 2) {
        float a = bf2[t];
#pragma unroll
        for (int k = 0; k < 32; ++k) a += sh[k] * Wf2[k * 2 + t];
        out[g * 2 + t] = 1.f / (1.f + expf(-a));
    }
}

extern "C" void kernel_launch(void* const* d_in, const int* in_sizes, int n_in,
                              void* d_out, int out_size, void* d_ws, size_t ws_size,
                              hipStream_t stream) {
    const float* x     = (const float*)d_in[0];
    const int*   ei    = (const int*)d_in[1];
    const int*   batch = (const int*)d_in[2];
    const float* W1 = (const float*)d_in[3];
    const float* b1 = (const float*)d_in[4];
    const float* g1 = (const float*)d_in[5];
    const float* be1 = (const float*)d_in[6];
    const float* rm1 = (const float*)d_in[7];
    const float* rv1 = (const float*)d_in[8];
    const float* W2 = (const float*)d_in[9];
    const float* b2 = (const float*)d_in[10];
    const float* g2 = (const float*)d_in[11];
    const float* be2 = (const float*)d_in[12];
    const float* rm2 = (const float*)d_in[13];
    const float* rv2 = (const float*)d_in[14];
    const float* W3 = (const float*)d_in[15];
    const float* b3 = (const float*)d_in[16];
    const float* g3 = (const float*)d_in[17];
    const float* be3 = (const float*)d_in[18];
    const float* rm3 = (const float*)d_in[19];
    const float* rv3 = (const float*)d_in[20];
    const float* Wf1 = (const float*)d_in[21];
    const float* bf1 = (const float*)d_in[22];
    const float* Wf2 = (const float*)d_in[23];
    const float* bf2 = (const float*)d_in[24];
    float* out = (float*)d_out;

    const int N = in_sizes[2];            // 100000
    const int E = in_sizes[1] / 2;        // 3200000
    const int G = out_size / 2;           // 256
    const int B = (N + BKN - 1) / BKN;    // buckets (196)

    char* ws = (char*)d_ws;
    size_t off = 0;
    auto alloc = [&](size_t bytes) {
        char* p = ws + off;
        off += (bytes + 255) & ~(size_t)255;
        return p;
    };
    float*         H3       = (float*)alloc((size_t)N * HF * sizeof(float));
    unsigned char* HS1      = (unsigned char*)alloc((size_t)N * HF);
    unsigned char* HS2      = (unsigned char*)alloc((size_t)N * HF);
    float*         xs       = (float*)alloc((size_t)N * 5 * sizeof(float));
    float*         dinv     = (float*)alloc((size_t)N * sizeof(float));
    int*           base     = (int*)  alloc(((size_t)N + 1) * sizeof(int));
    int*           bcnt     = (int*)  alloc((size_t)NBUCK_MAX * sizeof(int));
    int*           bbase2   = (int*)  alloc(((size_t)NBUCK_MAX + 1) * sizeof(int));
    int*           bcur     = (int*)  alloc((size_t)NBUCK_MAX * sizeof(int));
    int*           csr      = (int*)  alloc((size_t)E * sizeof(int));
    int*           stage    = (int*)H3;   // alias: consumed (passC) before H3 written (layer 3)

    const int* src = ei;
    const int* dst = ei + E;

    const int BT = 256;
    int gP  = (N * 5 + BT - 1) / BT;
    int gPB = (E + PB_TILE - 1) / PB_TILE;

    // ---- CSR build: bucket hist -> 196-scan -> run-reserving partition -> local scatter ----
    hipMemsetAsync(bcnt, 0, (size_t)B * sizeof(int), stream);
    k_bhist<<<gPB, PB_T, 0, stream>>>(dst, bcnt, E, B);
    k_bscan<<<1, 64, 0, stream>>>(bcnt, bbase2, bcur, base, B, N, E);
    k_passB<<<gPB, PB_T, 0, stream>>>(src, dst, bcur, stage, E, B);
    k_passC<<<B, 512, 0, stream>>>(stage, bbase2, base, dinv, csr, N);
    k_prescale<<<gP, BT, 0, stream>>>(x, dinv, xs, N * 5);

    // ---- fused layers (W columns in VGPRs; grid-stride over nodes) ----
    k_layer1<<<LGRID, BT, 0, stream>>>(xs, HS1, csr, base, dinv,
                                       W1, b1, g1, be1, rm1, rv1, N);
    k_layer<1><<<LGRID, BT, 0, stream>>>(HS1, HS2, csr, base, dinv,
                                         W2, b2, g2, be2, rm2, rv2, N);
    k_layer<0><<<LGRID, BT, 0, stream>>>(HS2, H3, csr, base, dinv,
                                         W3, b3, g3, be3, rm3, rv3, N);

    // ---- pool + MLP head ----
    k_pool_fc<<<G, BT, 0, stream>>>(H3, batch, Wf1, bf1, Wf2, bf2, out, N);
}

// Round 13
// 561.695 us; speedup vs baseline: 1.0050x; 1.0050x over previous
//
#include <hip/hip_runtime.h>
#include <hip/hip_bf16.h>

#define HF 64
#define EPS 1e-5f

#define BSH 9                    // bucket shift: 512 nodes / bucket
#define BKN (1 << BSH)           // 512 nodes per bucket
#define NBUCK_MAX 256            // >= ceil(N / BKN)
#define PB_T 256                 // passB threads
#define PB_EPT 32                // edges per thread
#define PB_TILE (PB_T * PB_EPT)  // 8192 edges per block

#define LGRID 1536               // k_layer grid; grid-stride over nodes

typedef __hip_bfloat16 bf16;

__device__ __forceinline__ unsigned char f32_to_fp8(float v) {
    int p = __builtin_amdgcn_cvt_pk_fp8_f32(v, v, 0, false);
    return (unsigned char)(p & 0xff);
}

__device__ __forceinline__ float bcast_lane(float v, int k) {
    return __uint_as_float(__builtin_amdgcn_readlane(__float_as_uint(v), k));
}

// ---- bucket histogram: LDS per-block, one global atomic per (block,bucket) ----
__global__ __launch_bounds__(PB_T) void k_bhist(const int* __restrict__ dst,
                                                int* __restrict__ bcnt, int E, int B) {
    __shared__ int bh[NBUCK_MAX];
    int t = threadIdx.x;
    for (int b = t; b < B; b += PB_T) bh[b] = 0;
    __syncthreads();
    int tile0 = blockIdx.x * PB_TILE;
#pragma unroll
    for (int k = 0; k < PB_EPT; ++k) {
        int e = tile0 + k * PB_T + t;
        if (e < E) atomicAdd(&bh[dst[e] >> BSH], 1);
    }
    __syncthreads();
    for (int b = t; b < B; b += PB_T) {
        int c = bh[b];
        if (c) atomicAdd(&bcnt[b], c);
    }
}

// ---- bucket scan: bbase2 = excl scan(bcnt); bcur = bbase2; base[N] = E ----
__global__ void k_bscan(const int* __restrict__ bcnt, int* __restrict__ bbase2,
                        int* __restrict__ bcur, int* __restrict__ base, int B, int N, int E) {
    if (threadIdx.x == 0 && blockIdx.x == 0) {
        int acc = 0;
        for (int i = 0; i < B; ++i) { bbase2[i] = acc; bcur[i] = acc; acc += bcnt[i]; }
        bbase2[B] = acc;   // == E
        base[N] = E;
    }
}

// ---- pass B: block-tiled binning; reserve per-(block,bucket) RUNS, write block-private ----
__global__ __launch_bounds__(PB_T) void k_passB(
    const int* __restrict__ src, const int* __restrict__ dst,
    int* __restrict__ bcur, int* __restrict__ stage, int E, int B) {
    __shared__ int scnt[NBUCK_MAX];
    __shared__ int sgoff[NBUCK_MAX];
    int t = threadIdx.x;
    int tile0 = blockIdx.x * PB_TILE;

    for (int b = t; b < B; b += PB_T) scnt[b] = 0;
    __syncthreads();

    int rec[PB_EPT];
    int bkt[PB_EPT];
#pragma unroll
    for (int k = 0; k < PB_EPT; ++k) {
        int e = tile0 + k * PB_T + t;
        bkt[k] = -1;
        if (e < E) {
            int d = dst[e];
            int s = src[e];
            int b = d >> BSH;
            bkt[k] = b;
            rec[k] = s | ((d & (BKN - 1)) << 17);
            atomicAdd(&scnt[b], 1);
        }
    }
    __syncthreads();

    for (int b = t; b < B; b += PB_T) {
        int c = scnt[b];
        sgoff[b] = c ? atomicAdd(&bcur[b], c) : 0;
        scnt[b] = 0;
    }
    __syncthreads();

#pragma unroll
    for (int k = 0; k < PB_EPT; ++k) {
        if (bkt[k] >= 0) {
            int loc = atomicAdd(&scnt[bkt[k]], 1);
            stage[sgoff[bkt[k]] + loc] = rec[k];
        }
    }
}

// ---- pass C: per bucket: LDS node-hist -> scan -> base/dinv -> scatter csr ----
__global__ __launch_bounds__(512) void k_passC(const int* __restrict__ stage,
                                               const int* __restrict__ bb2,
                                               int* __restrict__ base,
                                               float* __restrict__ dinv,
                                               int* __restrict__ csr, int N) {
    __shared__ int lcnt[BKN];
    __shared__ int lscan[BKN];
    __shared__ int lcur[BKN];
    int beta = blockIdx.x;
    int n0 = beta * BKN;
    int n1 = n0 + BKN; if (n1 > N) n1 = N;
    int nn = n1 - n0;
    int t = threadIdx.x;       // blockDim == 512 == BKN
    lcnt[t] = 0;
    __syncthreads();
    int rbeg = bb2[beta], rend = bb2[beta + 1];
    for (int i = rbeg + t; i < rend; i += 512)
        atomicAdd(&lcnt[stage[i] >> 17], 1);
    __syncthreads();
    int v = lcnt[t];
    lscan[t] = v;
    __syncthreads();
    for (int off = 1; off < 512; off <<= 1) {
        int val = lscan[t];
        int add = (t >= off) ? lscan[t - off] : 0;
        __syncthreads();
        lscan[t] = val + add;
        __syncthreads();
    }
    int b = rbeg + lscan[t] - v;   // exclusive scan + bucket start
    if (t < nn) {
        base[n0 + t] = b;
        dinv[n0 + t] = rsqrtf((float)v + 1.0f);
    }
    lcur[t] = b;
    __syncthreads();
    for (int i = rbeg + t; i < rend; i += 512) {
        int r = stage[i];
        int pos = atomicAdd(&lcur[r >> 17], 1);
        csr[pos] = r & 0x1ffff;
    }
}

// ---- prescale: xs[n,c] = x[n,c] * dinv[n] ----
__global__ void k_prescale(const float* __restrict__ x, const float* __restrict__ dinv,
                           float* __restrict__ xs, int N5) {
    int i = blockIdx.x * blockDim.x + threadIdx.x;
    if (i < N5) xs[i] = x[i] * dinv[i / 5];
}

// ---- layer 1 fused: W column in VGPRs, readlane matmul, grid-stride over nodes ----
__global__ __launch_bounds__(256, 4) void k_layer1(
    const float* __restrict__ xs, unsigned char* __restrict__ hout,
    const int* __restrict__ csr, const int* __restrict__ basep,
    const float* __restrict__ dinv,
    const float* __restrict__ W1, const float* __restrict__ b,
    const float* __restrict__ g, const float* __restrict__ be,
    const float* __restrict__ rm, const float* __restrict__ rv, int N) {
    int lane = threadIdx.x & 63;
    int wave = threadIdx.x >> 6;
    int stride = gridDim.x * 4;

    // per-lane folded params (lane == output feature f)
    float scale = g[lane] * rsqrtf(rv[lane] + EPS);
    float bias  = (b[lane] - rm[lane]) * scale + be[lane];
    float wcol[5];
#pragma unroll
    for (int k = 0; k < 5; ++k) wcol[k] = W1[k * HF + lane] * scale;

    for (int node = blockIdx.x * 4 + wave; node < N; node += stride) {
        int j   = __builtin_amdgcn_readfirstlane(basep[node]);
        int end = __builtin_amdgcn_readfirstlane(basep[node + 1]);

        float a0 = 0.f, a1 = 0.f, a2 = 0.f, a3 = 0.f;
        if (lane < 5) a0 = xs[node * 5 + lane];   // self term
        for (; j + 8 <= end; j += 8) {
            int s0 = csr[j+0], s1 = csr[j+1], s2 = csr[j+2], s3 = csr[j+3];
            int s4 = csr[j+4], s5 = csr[j+5], s6 = csr[j+6], s7 = csr[j+7];
            if (lane < 5) {
                float v0 = xs[s0 * 5 + lane], v1 = xs[s1 * 5 + lane];
                float v2 = xs[s2 * 5 + lane], v3 = xs[s3 * 5 + lane];
                float v4 = xs[s4 * 5 + lane], v5 = xs[s5 * 5 + lane];
                float v6 = xs[s6 * 5 + lane], v7 = xs[s7 * 5 + lane];
                a0 += v0; a1 += v1; a2 += v2; a3 += v3;
                a0 += v4; a1 += v5; a2 += v6; a3 += v7;
            }
        }
        for (; j < end; ++j) {
            int s = csr[j];
            if (lane < 5) a0 += xs[s * 5 + lane];
        }
        float di = dinv[node];
        float acc = ((a0 + a1) + (a2 + a3)) * di;

        float out = bias;
#pragma unroll
        for (int k = 0; k < 5; ++k) out += bcast_lane(acc, k) * wcol[k];
        out = fmaxf(out, 0.f);
        hout[(size_t)node * HF + lane] = f32_to_fp8(out * di);  // pre-scale for next layer
    }
}

// ---- layers 2/3 fused: fp8 gather, W column in VGPRs (128-reg budget), readlane matmul ----
// SCALE_OUT=1: write fp8 hs = h*dinv. SCALE_OUT=0: write fp32 h (feeds pool).
template <int SCALE_OUT>
__global__ __launch_bounds__(256, 4) void k_layer(
    const unsigned char* __restrict__ hs8, void* __restrict__ hout_v,
    const int* __restrict__ csr, const int* __restrict__ basep,
    const float* __restrict__ dinv,
    const float* __restrict__ W, const float* __restrict__ b,
    const float* __restrict__ g, const float* __restrict__ be,
    const float* __restrict__ rm, const float* __restrict__ rv, int N) {
    int lane = threadIdx.x & 63;
    int wave = threadIdx.x >> 6;
    int stride = gridDim.x * 4;

    // per-lane folded params (lane == output feature f); W column f in VGPRs
    float scale = g[lane] * rsqrtf(rv[lane] + EPS);
    float bias  = (b[lane] - rm[lane]) * scale + be[lane];
    float wcol[HF];
#pragma unroll
    for (int k = 0; k < HF; ++k) wcol[k] = W[k * HF + lane] * scale;

    const unsigned char* col = hs8 + lane;   // lane's feature column

    for (int node = blockIdx.x * 4 + wave; node < N; node += stride) {
        int j   = __builtin_amdgcn_readfirstlane(basep[node]);
        int end = __builtin_amdgcn_readfirstlane(basep[node + 1]);

        // self term (already *dinv[src])
        float a0 = __builtin_amdgcn_cvt_f32_fp8((unsigned)col[(size_t)node * HF], 0);
        float a1 = 0.f, a2 = 0.f, a3 = 0.f;

        // 8-wide MLP: 8 adjacent scalar index loads, then 8 independent byte-gathers
        for (; j + 8 <= end; j += 8) {
            int s0 = csr[j+0], s1 = csr[j+1], s2 = csr[j+2], s3 = csr[j+3];
            int s4 = csr[j+4], s5 = csr[j+5], s6 = csr[j+6], s7 = csr[j+7];
            unsigned u0 = col[(size_t)s0 * HF];
            unsigned u1 = col[(size_t)s1 * HF];
            unsigned u2 = col[(size_t)s2 * HF];
            unsigned u3 = col[(size_t)s3 * HF];
            unsigned u4 = col[(size_t)s4 * HF];
            unsigned u5 = col[(size_t)s5 * HF];
            unsigned u6 = col[(size_t)s6 * HF];
            unsigned u7 = col[(size_t)s7 * HF];
            a0 += __builtin_amdgcn_cvt_f32_fp8(u0, 0);
            a1 += __builtin_amdgcn_cvt_f32_fp8(u1, 0);
            a2 += __builtin_amdgcn_cvt_f32_fp8(u2, 0);
            a3 += __builtin_amdgcn_cvt_f32_fp8(u3, 0);
            a0 += __builtin_amdgcn_cvt_f32_fp8(u4, 0);
            a1 += __builtin_amdgcn_cvt_f32_fp8(u5, 0);
            a2 += __builtin_amdgcn_cvt_f32_fp8(u6, 0);
            a3 += __builtin_amdgcn_cvt_f32_fp8(u7, 0);
        }
        for (; j < end; ++j) {
            int s = csr[j];
            a0 += __builtin_amdgcn_cvt_f32_fp8((unsigned)col[(size_t)s * HF], 0);
        }
        float di = dinv[node];
        float acc = ((a0 + a1) + (a2 + a3)) * di;

        // matvec: out[f] = bias + sum_k acc_k * wcol[k]  (readlane broadcast, no LDS, no DS)
        float out = bias;
#pragma unroll
        for (int k = 0; k < HF; ++k) out += bcast_lane(acc, k) * wcol[k];
        out = fmaxf(out, 0.f);
        if (SCALE_OUT) {
            ((unsigned char*)hout_v)[(size_t)node * HF + lane] = f32_to_fp8(out * di);
        } else {
            ((float*)hout_v)[(size_t)node * HF + lane] = out;
        }
    }
}

// ---- per-graph mean-pool + FC(64->32) relu + FC(32->2) sigmoid ----
__global__ void k_pool_fc(const float* __restrict__ h, const int* __restrict__ batch,
                          const float* __restrict__ Wf1, const float* __restrict__ bf1,
                          const float* __restrict__ Wf2, const float* __restrict__ bf2,
                          float* __restrict__ out, int N) {
    int g = blockIdx.x;
    int t = threadIdx.x;
    int f = t & 63, q = t >> 6;

    int lo = 0, hi = N;
    while (lo < hi) { int mid = (lo + hi) >> 1; if (batch[mid] < g) lo = mid + 1; else hi = mid; }
    int start = lo;
    hi = N;
    while (lo < hi) { int mid = (lo + hi) >> 1; if (batch[mid] < g + 1) lo = mid + 1; else hi = mid; }
    int end = lo;

    float sum = 0.f;
    for (int n = start + q; n < end; n += 4) sum += h[n * HF + f];

    __shared__ float red[4][HF];
    __shared__ float sp[HF];
    __shared__ float sh[32];
    red[q][f] = sum;
    __syncthreads();
    if (q == 0) {
        float s = red[0][f] + red[1][f] + red[2][f] + red[3][f];
        float cntf = (float)(end - start);
        sp[f] = s / fmaxf(cntf, 1.0f);
    }
    __syncthreads();
    if (t < 32) {
        float a = bf1[t];
#pragma unroll
        for (int k = 0; k < HF; ++k) a += sp[k] * Wf1[k * 32 + t];
        sh[t] = fmaxf(a, 0.f);
    }
    __syncthreads();
    if (t < 2) {
        float a = bf2[t];
#pragma unroll
        for (int k = 0; k < 32; ++k) a += sh[k] * Wf2[k * 2 + t];
        out[g * 2 + t] = 1.f / (1.f + expf(-a));
    }
}

extern "C" void kernel_launch(void* const* d_in, const int* in_sizes, int n_in,
                              void* d_out, int out_size, void* d_ws, size_t ws_size,
                              hipStream_t stream) {
    const float* x     = (const float*)d_in[0];
    const int*   ei    = (const int*)d_in[1];
    const int*   batch = (const int*)d_in[2];
    const float* W1 = (const float*)d_in[3];
    const float* b1 = (const float*)d_in[4];
    const float* g1 = (const float*)d_in[5];
    const float* be1 = (const float*)d_in[6];
    const float* rm1 = (const float*)d_in[7];
    const float* rv1 = (const float*)d_in[8];
    const float* W2 = (const float*)d_in[9];
    const float* b2 = (const float*)d_in[10];
    const float* g2 = (const float*)d_in[11];
    const float* be2 = (const float*)d_in[12];
    const float* rm2 = (const float*)d_in[13];
    const float* rv2 = (const float*)d_in[14];
    const float* W3 = (const float*)d_in[15];
    const float* b3 = (const float*)d_in[16];
    const float* g3 = (const float*)d_in[17];
    const float* be3 = (const float*)d_in[18];
    const float* rm3 = (const float*)d_in[19];
    const float* rv3 = (const float*)d_in[20];
    const float* Wf1 = (const float*)d_in[21];
    const float* bf1 = (const float*)d_in[22];
    const float* Wf2 = (const float*)d_in[23];
    const float* bf2 = (const float*)d_in[24];
    float* out = (float*)d_out;

    const int N = in_sizes[2];            // 100000
    const int E = in_sizes[1] / 2;        // 3200000
    const int G = out_size / 2;           // 256
    const int B = (N + BKN - 1) / BKN;    // buckets (196)

    char* ws = (char*)d_ws;
    size_t off = 0;
    auto alloc = [&](size_t bytes) {
        char* p = ws + off;
        off += (bytes + 255) & ~(size_t)255;
        return p;
    };
    float*         H3       = (float*)alloc((size_t)N * HF * sizeof(float));
    unsigned char* HS1      = (unsigned char*)alloc((size_t)N * HF);
    unsigned char* HS2      = (unsigned char*)alloc((size_t)N * HF);
    float*         xs       = (float*)alloc((size_t)N * 5 * sizeof(float));
    float*         dinv     = (float*)alloc((size_t)N * sizeof(float));
    int*           base     = (int*)  alloc(((size_t)N + 1) * sizeof(int));
    int*           bcnt     = (int*)  alloc((size_t)NBUCK_MAX * sizeof(int));
    int*           bbase2   = (int*)  alloc(((size_t)NBUCK_MAX + 1) * sizeof(int));
    int*           bcur     = (int*)  alloc((size_t)NBUCK_MAX * sizeof(int));
    int*           csr      = (int*)  alloc((size_t)E * sizeof(int));
    int*           stage    = (int*)H3;   // alias: consumed (passC) before H3 written (layer 3)

    const int* src = ei;
    const int* dst = ei + E;

    const int BT = 256;
    int gP  = (N * 5 + BT - 1) / BT;
    int gPB = (E + PB_TILE - 1) / PB_TILE;

    // ---- CSR build: bucket hist -> 196-scan -> run-reserving partition -> local scatter ----
    hipMemsetAsync(bcnt, 0, (size_t)B * sizeof(int), stream);
    k_bhist<<<gPB, PB_T, 0, stream>>>(dst, bcnt, E, B);
    k_bscan<<<1, 64, 0, stream>>>(bcnt, bbase2, bcur, base, B, N, E);
    k_passB<<<gPB, PB_T, 0, stream>>>(src, dst, bcur, stage, E, B);
    k_passC<<<B, 512, 0, stream>>>(stage, bbase2, base, dinv, csr, N);
    k_prescale<<<gP, BT, 0, stream>>>(x, dinv, xs, N * 5);

    // ---- fused layers (W columns in VGPRs; grid-stride over nodes) ----
    k_layer1<<<LGRID, BT, 0, stream>>>(xs, HS1, csr, base, dinv,
                                       W1, b1, g1, be1, rm1, rv1, N);
    k_layer<1><<<LGRID, BT, 0, stream>>>(HS1, HS2, csr, base, dinv,
                                         W2, b2, g2, be2, rm2, rv2, N);
    k_layer<0><<<LGRID, BT, 0, stream>>>(HS2, H3, csr, base, dinv,
                                         W3, b3, g3, be3, rm3, rv3, N);

    // ---- pool + MLP head ----
    k_pool_fc<<<G, BT, 0, stream>>>(H3, batch, Wf1, bf1, Wf2, bf2, out, N);
}

// Round 14
// 561.380 us; speedup vs baseline: 1.0056x; 1.0006x over previous
//
#include <hip/hip_runtime.h>
#include <hip/hip_bf16.h>

#define HF 64
#define EPS 1e-5f

#define BSH 9                    // bucket shift: 512 nodes / bucket
#define BKN (1 << BSH)           // 512 nodes per bucket
#define NBUCK_MAX 256            // >= ceil(N / BKN)
#define PB_T 256                 // passB threads
#define PB_EPT 32                // edges per thread
#define PB_TILE (PB_T * PB_EPT)  // 8192 edges per block

#define LGRID 1536               // k_layer grid; grid-stride over node groups
#define TROW 144                 // LDS tile row stride (128 + 16 pad)

typedef __hip_bfloat16 bf16;
typedef __attribute__((ext_vector_type(8))) short short8;
typedef __attribute__((ext_vector_type(4))) float float4v;

__device__ __forceinline__ unsigned char f32_to_fp8(float v) {
    int p = __builtin_amdgcn_cvt_pk_fp8_f32(v, v, 0, false);
    return (unsigned char)(p & 0xff);
}

__device__ __forceinline__ unsigned short f32_bf16(float x) {
    unsigned u = __float_as_uint(x);
    return (unsigned short)((u + 0x7fffu + ((u >> 16) & 1u)) >> 16);
}

__device__ __forceinline__ float bcast_lane(float v, int k) {
    return __uint_as_float(__builtin_amdgcn_readlane(__float_as_uint(v), k));
}

// ---- bucket histogram: LDS per-block, one global atomic per (block,bucket) ----
__global__ __launch_bounds__(PB_T) void k_bhist(const int* __restrict__ dst,
                                                int* __restrict__ bcnt, int E, int B) {
    __shared__ int bh[NBUCK_MAX];
    int t = threadIdx.x;
    for (int b = t; b < B; b += PB_T) bh[b] = 0;
    __syncthreads();
    int tile0 = blockIdx.x * PB_TILE;
#pragma unroll
    for (int k = 0; k < PB_EPT; ++k) {
        int e = tile0 + k * PB_T + t;
        if (e < E) atomicAdd(&bh[dst[e] >> BSH], 1);
    }
    __syncthreads();
    for (int b = t; b < B; b += PB_T) {
        int c = bh[b];
        if (c) atomicAdd(&bcnt[b], c);
    }
}

// ---- bucket scan ----
__global__ void k_bscan(const int* __restrict__ bcnt, int* __restrict__ bbase2,
                        int* __restrict__ bcur, int* __restrict__ base, int B, int N, int E) {
    if (threadIdx.x == 0 && blockIdx.x == 0) {
        int acc = 0;
        for (int i = 0; i < B; ++i) { bbase2[i] = acc; bcur[i] = acc; acc += bcnt[i]; }
        bbase2[B] = acc;
        base[N] = E;
    }
}

// ---- pass B: run-reserving bucket partition ----
__global__ __launch_bounds__(PB_T) void k_passB(
    const int* __restrict__ src, const int* __restrict__ dst,
    int* __restrict__ bcur, int* __restrict__ stage, int E, int B) {
    __shared__ int scnt[NBUCK_MAX];
    __shared__ int sgoff[NBUCK_MAX];
    int t = threadIdx.x;
    int tile0 = blockIdx.x * PB_TILE;

    for (int b = t; b < B; b += PB_T) scnt[b] = 0;
    __syncthreads();

    int rec[PB_EPT];
    int bkt[PB_EPT];
#pragma unroll
    for (int k = 0; k < PB_EPT; ++k) {
        int e = tile0 + k * PB_T + t;
        bkt[k] = -1;
        if (e < E) {
            int d = dst[e];
            int s = src[e];
            int b = d >> BSH;
            bkt[k] = b;
            rec[k] = s | ((d & (BKN - 1)) << 17);
            atomicAdd(&scnt[b], 1);
        }
    }
    __syncthreads();

    for (int b = t; b < B; b += PB_T) {
        int c = scnt[b];
        sgoff[b] = c ? atomicAdd(&bcur[b], c) : 0;
        scnt[b] = 0;
    }
    __syncthreads();

#pragma unroll
    for (int k = 0; k < PB_EPT; ++k) {
        if (bkt[k] >= 0) {
            int loc = atomicAdd(&scnt[bkt[k]], 1);
            stage[sgoff[bkt[k]] + loc] = rec[k];
        }
    }
}

// ---- pass C: per bucket: LDS node-hist -> scan -> base/dinv -> scatter csr ----
__global__ __launch_bounds__(512) void k_passC(const int* __restrict__ stage,
                                               const int* __restrict__ bb2,
                                               int* __restrict__ base,
                                               float* __restrict__ dinv,
                                               int* __restrict__ csr, int N) {
    __shared__ int lcnt[BKN];
    __shared__ int lscan[BKN];
    __shared__ int lcur[BKN];
    int beta = blockIdx.x;
    int n0 = beta * BKN;
    int n1 = n0 + BKN; if (n1 > N) n1 = N;
    int nn = n1 - n0;
    int t = threadIdx.x;
    lcnt[t] = 0;
    __syncthreads();
    int rbeg = bb2[beta], rend = bb2[beta + 1];
    for (int i = rbeg + t; i < rend; i += 512)
        atomicAdd(&lcnt[stage[i] >> 17], 1);
    __syncthreads();
    int v = lcnt[t];
    lscan[t] = v;
    __syncthreads();
    for (int off = 1; off < 512; off <<= 1) {
        int val = lscan[t];
        int add = (t >= off) ? lscan[t - off] : 0;
        __syncthreads();
        lscan[t] = val + add;
        __syncthreads();
    }
    int b = rbeg + lscan[t] - v;
    if (t < nn) {
        base[n0 + t] = b;
        dinv[n0 + t] = rsqrtf((float)v + 1.0f);
    }
    lcur[t] = b;
    __syncthreads();
    for (int i = rbeg + t; i < rend; i += 512) {
        int r = stage[i];
        int pos = atomicAdd(&lcur[r >> 17], 1);
        csr[pos] = r & 0x1ffff;
    }
}

// ---- prescale: xs[n,c] = x[n,c] * dinv[n] ----
__global__ void k_prescale(const float* __restrict__ x, const float* __restrict__ dinv,
                           float* __restrict__ xs, int N5) {
    int i = blockIdx.x * blockDim.x + threadIdx.x;
    if (i < N5) xs[i] = x[i] * dinv[i / 5];
}

// ---- prep: fold BN into W (bf16), pre-swizzle into MFMA B-fragment order; fold bias ----
// wfrag[((nt*2+ks)*64 + lane)*8 + j] = bf16( W[ks*32+(lane>>4)*8+j][nt*16+(lane&15)] * scale_f )
__global__ void k_prep(const float* __restrict__ W, const float* __restrict__ b,
                       const float* __restrict__ g, const float* __restrict__ be,
                       const float* __restrict__ rm, const float* __restrict__ rv,
                       unsigned short* __restrict__ wfrag, float* __restrict__ biasf) {
    int t = threadIdx.x;
    if (t < HF) {
        float scale = g[t] * rsqrtf(rv[t] + EPS);
        biasf[t] = (b[t] - rm[t]) * scale + be[t];
    }
    for (int idx = t; idx < 8 * 64 * 8; idx += blockDim.x) {
        int j = idx & 7;
        int lane = (idx >> 3) & 63;
        int e = idx >> 9;              // nt*2+ks
        int nt = e >> 1, ks = e & 1;
        int k = ks * 32 + (lane >> 4) * 8 + j;
        int f = nt * 16 + (lane & 15);
        float scale = g[f] * rsqrtf(rv[f] + EPS);
        wfrag[idx] = f32_bf16(W[k * HF + f] * scale);
    }
}

// ---- layer 1 fused: small matvec via readlane (5 weights/lane) ----
__global__ __launch_bounds__(256, 4) void k_layer1(
    const float* __restrict__ xs, unsigned char* __restrict__ hout,
    const int* __restrict__ csr, const int* __restrict__ basep,
    const float* __restrict__ dinv,
    const float* __restrict__ W1, const float* __restrict__ b,
    const float* __restrict__ g, const float* __restrict__ be,
    const float* __restrict__ rm, const float* __restrict__ rv, int N) {
    int lane = threadIdx.x & 63;
    int wave = threadIdx.x >> 6;
    int stride = gridDim.x * 4;

    float scale = g[lane] * rsqrtf(rv[lane] + EPS);
    float bias  = (b[lane] - rm[lane]) * scale + be[lane];
    float w0 = W1[0 * HF + lane] * scale;
    float w1 = W1[1 * HF + lane] * scale;
    float w2 = W1[2 * HF + lane] * scale;
    float w3 = W1[3 * HF + lane] * scale;
    float w4 = W1[4 * HF + lane] * scale;

    for (int node = blockIdx.x * 4 + wave; node < N; node += stride) {
        int j   = __builtin_amdgcn_readfirstlane(basep[node]);
        int end = __builtin_amdgcn_readfirstlane(basep[node + 1]);

        float a0 = 0.f, a1 = 0.f, a2 = 0.f, a3 = 0.f;
        if (lane < 5) a0 = xs[node * 5 + lane];
        for (; j + 8 <= end; j += 8) {
            int s0 = csr[j+0], s1 = csr[j+1], s2 = csr[j+2], s3 = csr[j+3];
            int s4 = csr[j+4], s5 = csr[j+5], s6 = csr[j+6], s7 = csr[j+7];
            if (lane < 5) {
                float v0 = xs[s0 * 5 + lane], v1 = xs[s1 * 5 + lane];
                float v2 = xs[s2 * 5 + lane], v3 = xs[s3 * 5 + lane];
                float v4 = xs[s4 * 5 + lane], v5 = xs[s5 * 5 + lane];
                float v6 = xs[s6 * 5 + lane], v7 = xs[s7 * 5 + lane];
                a0 += v0; a1 += v1; a2 += v2; a3 += v3;
                a0 += v4; a1 += v5; a2 += v6; a3 += v7;
            }
        }
        for (; j < end; ++j) {
            int s = csr[j];
            if (lane < 5) a0 += xs[s * 5 + lane];
        }
        float di = dinv[node];
        float acc = ((a0 + a1) + (a2 + a3)) * di;

        float out = bias;
        out += bcast_lane(acc, 0) * w0;
        out += bcast_lane(acc, 1) * w1;
        out += bcast_lane(acc, 2) * w2;
        out += bcast_lane(acc, 3) * w3;
        out += bcast_lane(acc, 4) * w4;
        out = fmaxf(out, 0.f);
        hout[(size_t)node * HF + lane] = f32_to_fp8(out * di);
    }
}

// ---- layers 2/3: fp8 gather (16 nodes/wave) + MFMA epilogue ----
// SCALE_OUT=1: write fp8 hs = h*dinv. SCALE_OUT=0: write fp32 h (feeds pool).
template <int SCALE_OUT>
__global__ __launch_bounds__(256, 4) void k_layer(
    const unsigned char* __restrict__ hs8, void* __restrict__ hout_v,
    const int* __restrict__ csr, const int* __restrict__ basep,
    const float* __restrict__ dinv,
    const unsigned short* __restrict__ wfrag, const float* __restrict__ biasf, int N) {
    __shared__ unsigned char ldsbuf[4 * 16 * TROW];
    int lane = threadIdx.x & 63;
    int wave = threadIdx.x >> 6;
    int q = lane >> 4;
    unsigned char* tile = ldsbuf + wave * (16 * TROW);

    // B fragments (BN-folded W, bf16) resident in VGPRs: 8 x short8 = 32 regs
    short8 bfrag[8];
#pragma unroll
    for (int e = 0; e < 8; ++e) bfrag[e] = ((const short8*)wfrag)[e * 64 + lane];
    float biasv[4];
#pragma unroll
    for (int nt = 0; nt < 4; ++nt) biasv[nt] = biasf[nt * 16 + (lane & 15)];

    const unsigned char* col = hs8 + lane;
    int groups = (N + 15) >> 4;

    for (int grp = blockIdx.x * 4 + wave; grp < groups; grp += gridDim.x * 4) {
        int n0 = grp << 4;
        // ---- gather 16 nodes; stash acc (bf16) into the wave's LDS tile ----
        for (int i = 0; i < 16; ++i) {
            int node = n0 + i;
            float accv = 0.f;
            if (node < N) {
                int j   = __builtin_amdgcn_readfirstlane(basep[node]);
                int end = __builtin_amdgcn_readfirstlane(basep[node + 1]);
                float a0 = __builtin_amdgcn_cvt_f32_fp8((unsigned)col[(size_t)node * HF], 0);
                float a1 = 0.f, a2 = 0.f, a3 = 0.f;
                for (; j + 8 <= end; j += 8) {
                    int s0 = csr[j+0], s1 = csr[j+1], s2 = csr[j+2], s3 = csr[j+3];
                    int s4 = csr[j+4], s5 = csr[j+5], s6 = csr[j+6], s7 = csr[j+7];
                    unsigned u0 = col[(size_t)s0 * HF];
                    unsigned u1 = col[(size_t)s1 * HF];
                    unsigned u2 = col[(size_t)s2 * HF];
                    unsigned u3 = col[(size_t)s3 * HF];
                    unsigned u4 = col[(size_t)s4 * HF];
                    unsigned u5 = col[(size_t)s5 * HF];
                    unsigned u6 = col[(size_t)s6 * HF];
                    unsigned u7 = col[(size_t)s7 * HF];
                    a0 += __builtin_amdgcn_cvt_f32_fp8(u0, 0);
                    a1 += __builtin_amdgcn_cvt_f32_fp8(u1, 0);
                    a2 += __builtin_amdgcn_cvt_f32_fp8(u2, 0);
                    a3 += __builtin_amdgcn_cvt_f32_fp8(u3, 0);
                    a0 += __builtin_amdgcn_cvt_f32_fp8(u4, 0);
                    a1 += __builtin_amdgcn_cvt_f32_fp8(u5, 0);
                    a2 += __builtin_amdgcn_cvt_f32_fp8(u6, 0);
                    a3 += __builtin_amdgcn_cvt_f32_fp8(u7, 0);
                }
                for (; j < end; ++j) {
                    int s = csr[j];
                    a0 += __builtin_amdgcn_cvt_f32_fp8((unsigned)col[(size_t)s * HF], 0);
                }
                accv = ((a0 + a1) + (a2 + a3)) * dinv[node];
            }
            *(unsigned short*)(tile + i * TROW + lane * 2) = f32_bf16(accv);
        }

        // ---- MFMA: [16 nodes x 64k] @ [64k x 64f] ----
        float4v c0 = {0.f,0.f,0.f,0.f}, c1 = {0.f,0.f,0.f,0.f};
        float4v c2 = {0.f,0.f,0.f,0.f}, c3 = {0.f,0.f,0.f,0.f};
#pragma unroll
        for (int ks = 0; ks < 2; ++ks) {
            short8 a = *(const short8*)(tile + (lane & 15) * TROW + ks * 64 + q * 16);
            c0 = __builtin_amdgcn_mfma_f32_16x16x32_bf16(a, bfrag[0 * 2 + ks], c0, 0, 0, 0);
            c1 = __builtin_amdgcn_mfma_f32_16x16x32_bf16(a, bfrag[1 * 2 + ks], c1, 0, 0, 0);
            c2 = __builtin_amdgcn_mfma_f32_16x16x32_bf16(a, bfrag[2 * 2 + ks], c2, 0, 0, 0);
            c3 = __builtin_amdgcn_mfma_f32_16x16x32_bf16(a, bfrag[3 * 2 + ks], c3, 0, 0, 0);
        }

        // ---- epilogue: bias + ReLU (+ dinv scale for fp8 path) ----
        int f0 = lane & 15;
#pragma unroll
        for (int reg = 0; reg < 4; ++reg) {
            int node = n0 + q * 4 + reg;
            if (node < N) {
                float v0 = fmaxf(c0[reg] + biasv[0], 0.f);
                float v1 = fmaxf(c1[reg] + biasv[1], 0.f);
                float v2 = fmaxf(c2[reg] + biasv[2], 0.f);
                float v3 = fmaxf(c3[reg] + biasv[3], 0.f);
                if (SCALE_OUT) {
                    float di = dinv[node];
                    unsigned char* o = (unsigned char*)hout_v + (size_t)node * HF;
                    o[ 0 + f0] = f32_to_fp8(v0 * di);
                    o[16 + f0] = f32_to_fp8(v1 * di);
                    o[32 + f0] = f32_to_fp8(v2 * di);
                    o[48 + f0] = f32_to_fp8(v3 * di);
                } else {
                    float* o = (float*)hout_v + (size_t)node * HF;
                    o[ 0 + f0] = v0;
                    o[16 + f0] = v1;
                    o[32 + f0] = v2;
                    o[48 + f0] = v3;
                }
            }
        }
    }
}

// ---- per-graph mean-pool + FC(64->32) relu + FC(32->2) sigmoid ----
__global__ void k_pool_fc(const float* __restrict__ h, const int* __restrict__ batch,
                          const float* __restrict__ Wf1, const float* __restrict__ bf1,
                          const float* __restrict__ Wf2, const float* __restrict__ bf2,
                          float* __restrict__ out, int N) {
    int g = blockIdx.x;
    int t = threadIdx.x;
    int f = t & 63, q = t >> 6;

    int lo = 0, hi = N;
    while (lo < hi) { int mid = (lo + hi) >> 1; if (batch[mid] < g) lo = mid + 1; else hi = mid; }
    int start = lo;
    hi = N;
    while (lo < hi) { int mid = (lo + hi) >> 1; if (batch[mid] < g + 1) lo = mid + 1; else hi = mid; }
    int end = lo;

    float sum = 0.f;
    for (int n = start + q; n < end; n += 4) sum += h[n * HF + f];

    __shared__ float red[4][HF];
    __shared__ float sp[HF];
    __shared__ float sh[32];
    red[q][f] = sum;
    __syncthreads();
    if (q == 0) {
        float s = red[0][f] + red[1][f] + red[2][f] + red[3][f];
        float cntf = (float)(end - start);
        sp[f] = s / fmaxf(cntf, 1.0f);
    }
    __syncthreads();
    if (t < 32) {
        float a = bf1[t];
#pragma unroll
        for (int k = 0; k < HF; ++k) a += sp[k] * Wf1[k * 32 + t];
        sh[t] = fmaxf(a, 0.f);
    }
    __syncthreads();
    if (t < 2) {
        float a = bf2[t];
#pragma unroll
        for (int k = 0; k < 32; ++k) a += sh[k] * Wf2[k * 2 + t];
        out[g * 2 + t] = 1.f / (1.f + expf(-a));
    }
}

extern "C" void kernel_launch(void* const* d_in, const int* in_sizes, int n_in,
                              void* d_out, int out_size, void* d_ws, size_t ws_size,
                              hipStream_t stream) {
    const float* x     = (const float*)d_in[0];
    const int*   ei    = (const int*)d_in[1];
    const int*   batch = (const int*)d_in[2];
    const float* W1 = (const float*)d_in[3];
    const float* b1 = (const float*)d_in[4];
    const float* g1 = (const float*)d_in[5];
    const float* be1 = (const float*)d_in[6];
    const float* rm1 = (const float*)d_in[7];
    const float* rv1 = (const float*)d_in[8];
    const float* W2 = (const float*)d_in[9];
    const float* b2 = (const float*)d_in[10];
    const float* g2 = (const float*)d_in[11];
    const float* be2 = (const float*)d_in[12];
    const float* rm2 = (const float*)d_in[13];
    const float* rv2 = (const float*)d_in[14];
    const float* W3 = (const float*)d_in[15];
    const float* b3 = (const float*)d_in[16];
    const float* g3 = (const float*)d_in[17];
    const float* be3 = (const float*)d_in[18];
    const float* rm3 = (const float*)d_in[19];
    const float* rv3 = (const float*)d_in[20];
    const float* Wf1 = (const float*)d_in[21];
    const float* bf1 = (const float*)d_in[22];
    const float* Wf2 = (const float*)d_in[23];
    const float* bf2 = (const float*)d_in[24];
    float* out = (float*)d_out;

    const int N = in_sizes[2];            // 100000
    const int E = in_sizes[1] / 2;        // 3200000
    const int G = out_size / 2;           // 256
    const int B = (N + BKN - 1) / BKN;    // buckets (196)

    char* ws = (char*)d_ws;
    size_t off = 0;
    auto alloc = [&](size_t bytes) {
        char* p = ws + off;
        off += (bytes + 255) & ~(size_t)255;
        return p;
    };
    float*          H3     = (float*)alloc((size_t)N * HF * sizeof(float));
    unsigned char*  HS1    = (unsigned char*)alloc((size_t)N * HF);
    unsigned char*  HS2    = (unsigned char*)alloc((size_t)N * HF);
    float*          xs     = (float*)alloc((size_t)N * 5 * sizeof(float));
    float*          dinv   = (float*)alloc((size_t)N * sizeof(float));
    int*            base   = (int*)  alloc(((size_t)N + 1) * sizeof(int));
    int*            bcnt   = (int*)  alloc((size_t)NBUCK_MAX * sizeof(int));
    int*            bbase2 = (int*)  alloc(((size_t)NBUCK_MAX + 1) * sizeof(int));
    int*            bcur   = (int*)  alloc((size_t)NBUCK_MAX * sizeof(int));
    int*            csr    = (int*)  alloc((size_t)E * sizeof(int));
    unsigned short* wf2    = (unsigned short*)alloc(4096 * sizeof(unsigned short));
    unsigned short* wf3    = (unsigned short*)alloc(4096 * sizeof(unsigned short));
    float*          bia2   = (float*)alloc(HF * sizeof(float));
    float*          bia3   = (float*)alloc(HF * sizeof(float));
    int*            stage  = (int*)H3;   // alias: consumed (passC) before H3 written (layer 3)

    const int* src = ei;
    const int* dst = ei + E;

    const int BT = 256;
    int gP  = (N * 5 + BT - 1) / BT;
    int gPB = (E + PB_TILE - 1) / PB_TILE;

    // ---- weight prep (fold BN, bf16, fragment order) ----
    k_prep<<<1, 256, 0, stream>>>(W2, b2, g2, be2, rm2, rv2, wf2, bia2);
    k_prep<<<1, 256, 0, stream>>>(W3, b3, g3, be3, rm3, rv3, wf3, bia3);

    // ---- CSR build ----
    hipMemsetAsync(bcnt, 0, (size_t)B * sizeof(int), stream);
    k_bhist<<<gPB, PB_T, 0, stream>>>(dst, bcnt, E, B);
    k_bscan<<<1, 64, 0, stream>>>(bcnt, bbase2, bcur, base, B, N, E);
    k_passB<<<gPB, PB_T, 0, stream>>>(src, dst, bcur, stage, E, B);
    k_passC<<<B, 512, 0, stream>>>(stage, bbase2, base, dinv, csr, N);
    k_prescale<<<gP, BT, 0, stream>>>(x, dinv, xs, N * 5);

    // ---- fused layers ----
    k_layer1<<<LGRID, BT, 0, stream>>>(xs, HS1, csr, base, dinv,
                                       W1, b1, g1, be1, rm1, rv1, N);
    k_layer<1><<<LGRID, BT, 0, stream>>>(HS1, HS2, csr, base, dinv, wf2, bia2, N);
    k_layer<0><<<LGRID, BT, 0, stream>>>(HS2, H3, csr, base, dinv, wf3, bia3, N);

    // ---- pool + MLP head ----
    k_pool_fc<<<G, BT, 0, stream>>>(H3, batch, Wf1, bf1, Wf2, bf2, out, N);
}

// Round 15
// 533.549 us; speedup vs baseline: 1.0580x; 1.0522x over previous
//
#include <hip/hip_runtime.h>
#include <hip/hip_bf16.h>

#define HF 64
#define EPS 1e-5f

#define BSH 9                    // bucket shift: 512 nodes / bucket
#define BKN (1 << BSH)           // 512 nodes per bucket
#define NBUCK_MAX 256            // >= ceil(N / BKN)
#define PB_T 256                 // passB threads
#define PB_EPT 32                // edges per thread
#define PB_TILE (PB_T * PB_EPT)  // 8192 edges per block

#define LGRID 1568               // k_layer grid; waves >= 16-node groups (6250)
#define TROW 144                 // LDS tile row stride (128 + 16 pad)

typedef __hip_bfloat16 bf16;
typedef __attribute__((ext_vector_type(8))) short short8;
typedef __attribute__((ext_vector_type(4))) float float4v;

__device__ __forceinline__ unsigned char f32_to_fp8(float v) {
    int p = __builtin_amdgcn_cvt_pk_fp8_f32(v, v, 0, false);
    return (unsigned char)(p & 0xff);
}

__device__ __forceinline__ unsigned short f32_bf16(float x) {
    unsigned u = __float_as_uint(x);
    return (unsigned short)((u + 0x7fffu + ((u >> 16) & 1u)) >> 16);
}

__device__ __forceinline__ float bcast_lane(float v, int k) {
    return __uint_as_float(__builtin_amdgcn_readlane(__float_as_uint(v), k));
}

// ---- bucket histogram: LDS per-block, one global atomic per (block,bucket) ----
__global__ __launch_bounds__(PB_T) void k_bhist(const int* __restrict__ dst,
                                                int* __restrict__ bcnt, int E, int B) {
    __shared__ int bh[NBUCK_MAX];
    int t = threadIdx.x;
    for (int b = t; b < B; b += PB_T) bh[b] = 0;
    __syncthreads();
    int tile0 = blockIdx.x * PB_TILE;
#pragma unroll
    for (int k = 0; k < PB_EPT; ++k) {
        int e = tile0 + k * PB_T + t;
        if (e < E) atomicAdd(&bh[dst[e] >> BSH], 1);
    }
    __syncthreads();
    for (int b = t; b < B; b += PB_T) {
        int c = bh[b];
        if (c) atomicAdd(&bcnt[b], c);
    }
}

// ---- bucket scan ----
__global__ void k_bscan(const int* __restrict__ bcnt, int* __restrict__ bbase2,
                        int* __restrict__ bcur, int* __restrict__ base, int B, int N, int E) {
    if (threadIdx.x == 0 && blockIdx.x == 0) {
        int acc = 0;
        for (int i = 0; i < B; ++i) { bbase2[i] = acc; bcur[i] = acc; acc += bcnt[i]; }
        bbase2[B] = acc;
        base[N] = E;
    }
}

// ---- pass B: run-reserving bucket partition ----
__global__ __launch_bounds__(PB_T) void k_passB(
    const int* __restrict__ src, const int* __restrict__ dst,
    int* __restrict__ bcur, int* __restrict__ stage, int E, int B) {
    __shared__ int scnt[NBUCK_MAX];
    __shared__ int sgoff[NBUCK_MAX];
    int t = threadIdx.x;
    int tile0 = blockIdx.x * PB_TILE;

    for (int b = t; b < B; b += PB_T) scnt[b] = 0;
    __syncthreads();

    int rec[PB_EPT];
    int bkt[PB_EPT];
#pragma unroll
    for (int k = 0; k < PB_EPT; ++k) {
        int e = tile0 + k * PB_T + t;
        bkt[k] = -1;
        if (e < E) {
            int d = dst[e];
            int s = src[e];
            int b = d >> BSH;
            bkt[k] = b;
            rec[k] = s | ((d & (BKN - 1)) << 17);
            atomicAdd(&scnt[b], 1);
        }
    }
    __syncthreads();

    for (int b = t; b < B; b += PB_T) {
        int c = scnt[b];
        sgoff[b] = c ? atomicAdd(&bcur[b], c) : 0;
        scnt[b] = 0;
    }
    __syncthreads();

#pragma unroll
    for (int k = 0; k < PB_EPT; ++k) {
        if (bkt[k] >= 0) {
            int loc = atomicAdd(&scnt[bkt[k]], 1);
            stage[sgoff[bkt[k]] + loc] = rec[k];
        }
    }
}

// ---- pass C: per bucket: LDS node-hist -> scan -> base/dinv -> scatter csr ----
__global__ __launch_bounds__(512) void k_passC(const int* __restrict__ stage,
                                               const int* __restrict__ bb2,
                                               int* __restrict__ base,
                                               float* __restrict__ dinv,
                                               int* __restrict__ csr, int N) {
    __shared__ int lcnt[BKN];
    __shared__ int lscan[BKN];
    __shared__ int lcur[BKN];
    int beta = blockIdx.x;
    int n0 = beta * BKN;
    int n1 = n0 + BKN; if (n1 > N) n1 = N;
    int nn = n1 - n0;
    int t = threadIdx.x;
    lcnt[t] = 0;
    __syncthreads();
    int rbeg = bb2[beta], rend = bb2[beta + 1];
    for (int i = rbeg + t; i < rend; i += 512)
        atomicAdd(&lcnt[stage[i] >> 17], 1);
    __syncthreads();
    int v = lcnt[t];
    lscan[t] = v;
    __syncthreads();
    for (int off = 1; off < 512; off <<= 1) {
        int val = lscan[t];
        int add = (t >= off) ? lscan[t - off] : 0;
        __syncthreads();
        lscan[t] = val + add;
        __syncthreads();
    }
    int b = rbeg + lscan[t] - v;
    if (t < nn) {
        base[n0 + t] = b;
        dinv[n0 + t] = rsqrtf((float)v + 1.0f);
    }
    lcur[t] = b;
    __syncthreads();
    for (int i = rbeg + t; i < rend; i += 512) {
        int r = stage[i];
        int pos = atomicAdd(&lcur[r >> 17], 1);
        csr[pos] = r & 0x1ffff;
    }
}

// ---- prescale: xs[n,c] = x[n,c] * dinv[n] ----
__global__ void k_prescale(const float* __restrict__ x, const float* __restrict__ dinv,
                           float* __restrict__ xs, int N5) {
    int i = blockIdx.x * blockDim.x + threadIdx.x;
    if (i < N5) xs[i] = x[i] * dinv[i / 5];
}

// ---- prep: fold BN into W (bf16), pre-swizzle into MFMA B-fragment order; fold bias ----
__global__ void k_prep(const float* __restrict__ W, const float* __restrict__ b,
                       const float* __restrict__ g, const float* __restrict__ be,
                       const float* __restrict__ rm, const float* __restrict__ rv,
                       unsigned short* __restrict__ wfrag, float* __restrict__ biasf) {
    int t = threadIdx.x;
    if (t < HF) {
        float scale = g[t] * rsqrtf(rv[t] + EPS);
        biasf[t] = (b[t] - rm[t]) * scale + be[t];
    }
    for (int idx = t; idx < 8 * 64 * 8; idx += blockDim.x) {
        int j = idx & 7;
        int lane = (idx >> 3) & 63;
        int e = idx >> 9;              // nt*2+ks
        int nt = e >> 1, ks = e & 1;
        int k = ks * 32 + (lane >> 4) * 8 + j;
        int f = nt * 16 + (lane & 15);
        float scale = g[f] * rsqrtf(rv[f] + EPS);
        wfrag[idx] = f32_bf16(W[k * HF + f] * scale);
    }
}

// ---- layer 1 fused: small matvec via readlane (5 weights/lane) ----
__global__ __launch_bounds__(256, 4) void k_layer1(
    const float* __restrict__ xs, unsigned char* __restrict__ hout,
    const int* __restrict__ csr, const int* __restrict__ basep,
    const float* __restrict__ dinv,
    const float* __restrict__ W1, const float* __restrict__ b,
    const float* __restrict__ g, const float* __restrict__ be,
    const float* __restrict__ rm, const float* __restrict__ rv, int N) {
    int lane = threadIdx.x & 63;
    int wave = threadIdx.x >> 6;
    int stride = gridDim.x * 4;

    float scale = g[lane] * rsqrtf(rv[lane] + EPS);
    float bias  = (b[lane] - rm[lane]) * scale + be[lane];
    float w0 = W1[0 * HF + lane] * scale;
    float w1 = W1[1 * HF + lane] * scale;
    float w2 = W1[2 * HF + lane] * scale;
    float w3 = W1[3 * HF + lane] * scale;
    float w4 = W1[4 * HF + lane] * scale;

    for (int node = blockIdx.x * 4 + wave; node < N; node += stride) {
        int j   = __builtin_amdgcn_readfirstlane(basep[node]);
        int end = __builtin_amdgcn_readfirstlane(basep[node + 1]);

        float a0 = 0.f, a1 = 0.f, a2 = 0.f, a3 = 0.f;
        if (lane < 5) a0 = xs[node * 5 + lane];
        for (; j + 8 <= end; j += 8) {
            int s0 = csr[j+0], s1 = csr[j+1], s2 = csr[j+2], s3 = csr[j+3];
            int s4 = csr[j+4], s5 = csr[j+5], s6 = csr[j+6], s7 = csr[j+7];
            if (lane < 5) {
                float v0 = xs[s0 * 5 + lane], v1 = xs[s1 * 5 + lane];
                float v2 = xs[s2 * 5 + lane], v3 = xs[s3 * 5 + lane];
                float v4 = xs[s4 * 5 + lane], v5 = xs[s5 * 5 + lane];
                float v6 = xs[s6 * 5 + lane], v7 = xs[s7 * 5 + lane];
                a0 += v0; a1 += v1; a2 += v2; a3 += v3;
                a0 += v4; a1 += v5; a2 += v6; a3 += v7;
            }
        }
        for (; j < end; ++j) {
            int s = csr[j];
            if (lane < 5) a0 += xs[s * 5 + lane];
        }
        float di = dinv[node];
        float acc = ((a0 + a1) + (a2 + a3)) * di;

        float out = bias;
        out += bcast_lane(acc, 0) * w0;
        out += bcast_lane(acc, 1) * w1;
        out += bcast_lane(acc, 2) * w2;
        out += bcast_lane(acc, 3) * w3;
        out += bcast_lane(acc, 4) * w4;
        out = fmaxf(out, 0.f);
        hout[(size_t)node * HF + lane] = f32_to_fp8(out * di);
    }
}

// ---- layers 2/3: dual-node interleaved fp8 gather (vector-index + readlane) + MFMA ----
// SCALE_OUT=1: write fp8 hs = h*dinv. SCALE_OUT=0: write fp32 h (feeds pool).
template <int SCALE_OUT>
__global__ __launch_bounds__(256, 4) void k_layer(
    const unsigned char* __restrict__ hs8, void* __restrict__ hout_v,
    const int* __restrict__ csr, const int* __restrict__ basep,
    const float* __restrict__ dinv,
    const unsigned short* __restrict__ wfrag, const float* __restrict__ biasf, int N) {
    __shared__ unsigned char ldsbuf[4 * 16 * TROW];
    int lane = threadIdx.x & 63;
    int wave = threadIdx.x >> 6;
    int q = lane >> 4;
    unsigned char* tile = ldsbuf + wave * (16 * TROW);

    // B fragments (BN-folded W, bf16) resident in VGPRs: 8 x short8 = 32 regs
    short8 bfrag[8];
#pragma unroll
    for (int e = 0; e < 8; ++e) bfrag[e] = ((const short8*)wfrag)[e * 64 + lane];
    float biasv[4];
#pragma unroll
    for (int nt = 0; nt < 4; ++nt) biasv[nt] = biasf[nt * 16 + (lane & 15)];

    const unsigned char* col = hs8 + lane;
    int groups = (N + 15) >> 4;

    for (int grp = blockIdx.x * 4 + wave; grp < groups; grp += gridDim.x * 4) {
        int n0 = grp << 4;
        // ---- gather 16 nodes as 8 interleaved pairs ----
        for (int i = 0; i < 16; i += 2) {
            int nA = n0 + i, nB = n0 + i + 1;
            bool vB = (nB < N);
            int jA   = __builtin_amdgcn_readfirstlane(basep[nA]);
            int eA   = __builtin_amdgcn_readfirstlane(basep[nA + 1]);
            int jB   = vB ? __builtin_amdgcn_readfirstlane(basep[nB])     : 0;
            int eB   = vB ? __builtin_amdgcn_readfirstlane(basep[nB + 1]) : 0;

            // self terms
            float aA0 = (nA < N) ? __builtin_amdgcn_cvt_f32_fp8((unsigned)col[(size_t)nA * HF], 0) : 0.f;
            float aB0 = vB ? __builtin_amdgcn_cvt_f32_fp8((unsigned)col[(size_t)nB * HF], 0) : 0.f;
            float aA1 = 0.f, aA2 = 0.f, aA3 = 0.f;
            float aB1 = 0.f, aB2 = 0.f, aB3 = 0.f;

            for (;;) {
                int cA = eA - jA; if (cA > 64) cA = 64; if (cA < 0) cA = 0;
                int cB = eB - jB; if (cB > 64) cB = 64; if (cB < 0) cB = 0;
                if ((cA | cB) == 0) break;
                // coalesced per-lane index fetch (may over-read past row end: csr has
                // slack after it in the workspace, values unused)
                int vidxA = 0, vidxB = 0;
                if (cA > 0) vidxA = csr[jA + lane];
                if (cB > 0) vidxB = csr[jB + lane];

                int kA = 0, kB = 0;
                // merged dual-chain: 8 A-gathers + 8 B-gathers in flight
                while (kA + 8 <= cA && kB + 8 <= cB) {
                    int sA0 = __builtin_amdgcn_readlane(vidxA, kA+0);
                    int sA1 = __builtin_amdgcn_readlane(vidxA, kA+1);
                    int sA2 = __builtin_amdgcn_readlane(vidxA, kA+2);
                    int sA3 = __builtin_amdgcn_readlane(vidxA, kA+3);
                    int sA4 = __builtin_amdgcn_readlane(vidxA, kA+4);
                    int sA5 = __builtin_amdgcn_readlane(vidxA, kA+5);
                    int sA6 = __builtin_amdgcn_readlane(vidxA, kA+6);
                    int sA7 = __builtin_amdgcn_readlane(vidxA, kA+7);
                    int sB0 = __builtin_amdgcn_readlane(vidxB, kB+0);
                    int sB1 = __builtin_amdgcn_readlane(vidxB, kB+1);
                    int sB2 = __builtin_amdgcn_readlane(vidxB, kB+2);
                    int sB3 = __builtin_amdgcn_readlane(vidxB, kB+3);
                    int sB4 = __builtin_amdgcn_readlane(vidxB, kB+4);
                    int sB5 = __builtin_amdgcn_readlane(vidxB, kB+5);
                    int sB6 = __builtin_amdgcn_readlane(vidxB, kB+6);
                    int sB7 = __builtin_amdgcn_readlane(vidxB, kB+7);
                    unsigned uA0 = col[(size_t)sA0 * HF];
                    unsigned uA1 = col[(size_t)sA1 * HF];
                    unsigned uA2 = col[(size_t)sA2 * HF];
                    unsigned uA3 = col[(size_t)sA3 * HF];
                    unsigned uA4 = col[(size_t)sA4 * HF];
                    unsigned uA5 = col[(size_t)sA5 * HF];
                    unsigned uA6 = col[(size_t)sA6 * HF];
                    unsigned uA7 = col[(size_t)sA7 * HF];
                    unsigned uB0 = col[(size_t)sB0 * HF];
                    unsigned uB1 = col[(size_t)sB1 * HF];
                    unsigned uB2 = col[(size_t)sB2 * HF];
                    unsigned uB3 = col[(size_t)sB3 * HF];
                    unsigned uB4 = col[(size_t)sB4 * HF];
                    unsigned uB5 = col[(size_t)sB5 * HF];
                    unsigned uB6 = col[(size_t)sB6 * HF];
                    unsigned uB7 = col[(size_t)sB7 * HF];
                    aA0 += __builtin_amdgcn_cvt_f32_fp8(uA0, 0);
                    aA1 += __builtin_amdgcn_cvt_f32_fp8(uA1, 0);
                    aA2 += __builtin_amdgcn_cvt_f32_fp8(uA2, 0);
                    aA3 += __builtin_amdgcn_cvt_f32_fp8(uA3, 0);
                    aA0 += __builtin_amdgcn_cvt_f32_fp8(uA4, 0);
                    aA1 += __builtin_amdgcn_cvt_f32_fp8(uA5, 0);
                    aA2 += __builtin_amdgcn_cvt_f32_fp8(uA6, 0);
                    aA3 += __builtin_amdgcn_cvt_f32_fp8(uA7, 0);
                    aB0 += __builtin_amdgcn_cvt_f32_fp8(uB0, 0);
                    aB1 += __builtin_amdgcn_cvt_f32_fp8(uB1, 0);
                    aB2 += __builtin_amdgcn_cvt_f32_fp8(uB2, 0);
                    aB3 += __builtin_amdgcn_cvt_f32_fp8(uB3, 0);
                    aB0 += __builtin_amdgcn_cvt_f32_fp8(uB4, 0);
                    aB1 += __builtin_amdgcn_cvt_f32_fp8(uB5, 0);
                    aB2 += __builtin_amdgcn_cvt_f32_fp8(uB6, 0);
                    aB3 += __builtin_amdgcn_cvt_f32_fp8(uB7, 0);
                    kA += 8; kB += 8;
                }
                // drain A 8-wide
                while (kA + 8 <= cA) {
                    int s0 = __builtin_amdgcn_readlane(vidxA, kA+0);
                    int s1 = __builtin_amdgcn_readlane(vidxA, kA+1);
                    int s2 = __builtin_amdgcn_readlane(vidxA, kA+2);
                    int s3 = __builtin_amdgcn_readlane(vidxA, kA+3);
                    int s4 = __builtin_amdgcn_readlane(vidxA, kA+4);
                    int s5 = __builtin_amdgcn_readlane(vidxA, kA+5);
                    int s6 = __builtin_amdgcn_readlane(vidxA, kA+6);
                    int s7 = __builtin_amdgcn_readlane(vidxA, kA+7);
                    unsigned u0 = col[(size_t)s0 * HF];
                    unsigned u1 = col[(size_t)s1 * HF];
                    unsigned u2 = col[(size_t)s2 * HF];
                    unsigned u3 = col[(size_t)s3 * HF];
                    unsigned u4 = col[(size_t)s4 * HF];
                    unsigned u5 = col[(size_t)s5 * HF];
                    unsigned u6 = col[(size_t)s6 * HF];
                    unsigned u7 = col[(size_t)s7 * HF];
                    aA0 += __builtin_amdgcn_cvt_f32_fp8(u0, 0);
                    aA1 += __builtin_amdgcn_cvt_f32_fp8(u1, 0);
                    aA2 += __builtin_amdgcn_cvt_f32_fp8(u2, 0);
                    aA3 += __builtin_amdgcn_cvt_f32_fp8(u3, 0);
                    aA0 += __builtin_amdgcn_cvt_f32_fp8(u4, 0);
                    aA1 += __builtin_amdgcn_cvt_f32_fp8(u5, 0);
                    aA2 += __builtin_amdgcn_cvt_f32_fp8(u6, 0);
                    aA3 += __builtin_amdgcn_cvt_f32_fp8(u7, 0);
                    kA += 8;
                }
                // drain B 8-wide
                while (kB + 8 <= cB) {
                    int s0 = __builtin_amdgcn_readlane(vidxB, kB+0);
                    int s1 = __builtin_amdgcn_readlane(vidxB, kB+1);
                    int s2 = __builtin_amdgcn_readlane(vidxB, kB+2);
                    int s3 = __builtin_amdgcn_readlane(vidxB, kB+3);
                    int s4 = __builtin_amdgcn_readlane(vidxB, kB+4);
                    int s5 = __builtin_amdgcn_readlane(vidxB, kB+5);
                    int s6 = __builtin_amdgcn_readlane(vidxB, kB+6);
                    int s7 = __builtin_amdgcn_readlane(vidxB, kB+7);
                    unsigned u0 = col[(size_t)s0 * HF];
                    unsigned u1 = col[(size_t)s1 * HF];
                    unsigned u2 = col[(size_t)s2 * HF];
                    unsigned u3 = col[(size_t)s3 * HF];
                    unsigned u4 = col[(size_t)s4 * HF];
                    unsigned u5 = col[(size_t)s5 * HF];
                    unsigned u6 = col[(size_t)s6 * HF];
                    unsigned u7 = col[(size_t)s7 * HF];
                    aB0 += __builtin_amdgcn_cvt_f32_fp8(u0, 0);
                    aB1 += __builtin_amdgcn_cvt_f32_fp8(u1, 0);
                    aB2 += __builtin_amdgcn_cvt_f32_fp8(u2, 0);
                    aB3 += __builtin_amdgcn_cvt_f32_fp8(u3, 0);
                    aB0 += __builtin_amdgcn_cvt_f32_fp8(u4, 0);
                    aB1 += __builtin_amdgcn_cvt_f32_fp8(u5, 0);
                    aB2 += __builtin_amdgcn_cvt_f32_fp8(u6, 0);
                    aB3 += __builtin_amdgcn_cvt_f32_fp8(u7, 0);
                    kB += 8;
                }
                // scalar tails
                for (; kA < cA; ++kA) {
                    int s = __builtin_amdgcn_readlane(vidxA, kA);
                    aA0 += __builtin_amdgcn_cvt_f32_fp8((unsigned)col[(size_t)s * HF], 0);
                }
                for (; kB < cB; ++kB) {
                    int s = __builtin_amdgcn_readlane(vidxB, kB);
                    aB0 += __builtin_amdgcn_cvt_f32_fp8((unsigned)col[(size_t)s * HF], 0);
                }
                jA += cA; jB += cB;
            }

            float accA = (nA < N) ? ((aA0 + aA1) + (aA2 + aA3)) * dinv[nA] : 0.f;
            float accB = vB ? ((aB0 + aB1) + (aB2 + aB3)) * dinv[nB] : 0.f;
            *(unsigned short*)(tile + i * TROW + lane * 2)       = f32_bf16(accA);
            *(unsigned short*)(tile + (i + 1) * TROW + lane * 2) = f32_bf16(accB);
        }

        // ---- MFMA: [16 nodes x 64k] @ [64k x 64f] ----
        float4v c0 = {0.f,0.f,0.f,0.f}, c1 = {0.f,0.f,0.f,0.f};
        float4v c2 = {0.f,0.f,0.f,0.f}, c3 = {0.f,0.f,0.f,0.f};
#pragma unroll
        for (int ks = 0; ks < 2; ++ks) {
            short8 a = *(const short8*)(tile + (lane & 15) * TROW + ks * 64 + q * 16);
            c0 = __builtin_amdgcn_mfma_f32_16x16x32_bf16(a, bfrag[0 * 2 + ks], c0, 0, 0, 0);
            c1 = __builtin_amdgcn_mfma_f32_16x16x32_bf16(a, bfrag[1 * 2 + ks], c1, 0, 0, 0);
            c2 = __builtin_amdgcn_mfma_f32_16x16x32_bf16(a, bfrag[2 * 2 + ks], c2, 0, 0, 0);
            c3 = __builtin_amdgcn_mfma_f32_16x16x32_bf16(a, bfrag[3 * 2 + ks], c3, 0, 0, 0);
        }

        // ---- epilogue: bias + ReLU (+ dinv scale for fp8 path) ----
        int f0 = lane & 15;
#pragma unroll
        for (int reg = 0; reg < 4; ++reg) {
            int node = n0 + q * 4 + reg;
            if (node < N) {
                float v0 = fmaxf(c0[reg] + biasv[0], 0.f);
                float v1 = fmaxf(c1[reg] + biasv[1], 0.f);
                float v2 = fmaxf(c2[reg] + biasv[2], 0.f);
                float v3 = fmaxf(c3[reg] + biasv[3], 0.f);
                if (SCALE_OUT) {
                    float di = dinv[node];
                    unsigned char* o = (unsigned char*)hout_v + (size_t)node * HF;
                    o[ 0 + f0] = f32_to_fp8(v0 * di);
                    o[16 + f0] = f32_to_fp8(v1 * di);
                    o[32 + f0] = f32_to_fp8(v2 * di);
                    o[48 + f0] = f32_to_fp8(v3 * di);
                } else {
                    float* o = (float*)hout_v + (size_t)node * HF;
                    o[ 0 + f0] = v0;
                    o[16 + f0] = v1;
                    o[32 + f0] = v2;
                    o[48 + f0] = v3;
                }
            }
        }
    }
}

// ---- per-graph mean-pool + FC(64->32) relu + FC(32->2) sigmoid ----
__global__ void k_pool_fc(const float* __restrict__ h, const int* __restrict__ batch,
                          const float* __restrict__ Wf1, const float* __restrict__ bf1,
                          const float* __restrict__ Wf2, const float* __restrict__ bf2,
                          float* __restrict__ out, int N) {
    int g = blockIdx.x;
    int t = threadIdx.x;
    int f = t & 63, q = t >> 6;

    int lo = 0, hi = N;
    while (lo < hi) { int mid = (lo + hi) >> 1; if (batch[mid] < g) lo = mid + 1; else hi = mid; }
    int start = lo;
    hi = N;
    while (lo < hi) { int mid = (lo + hi) >> 1; if (batch[mid] < g + 1) lo = mid + 1; else hi = mid; }
    int end = lo;

    float sum = 0.f;
    for (int n = start + q; n < end; n += 4) sum += h[n * HF + f];

    __shared__ float red[4][HF];
    __shared__ float sp[HF];
    __shared__ float sh[32];
    red[q][f] = sum;
    __syncthreads();
    if (q == 0) {
        float s = red[0][f] + red[1][f] + red[2][f] + red[3][f];
        float cntf = (float)(end - start);
        sp[f] = s / fmaxf(cntf, 1.0f);
    }
    __syncthreads();
    if (t < 32) {
        float a = bf1[t];
#pragma unroll
        for (int k = 0; k < HF; ++k) a += sp[k] * Wf1[k * 32 + t];
        sh[t] = fmaxf(a, 0.f);
    }
    __syncthreads();
    if (t < 2) {
        float a = bf2[t];
#pragma unroll
        for (int k = 0; k < 32; ++k) a += sh[k] * Wf2[k * 2 + t];
        out[g * 2 + t] = 1.f / (1.f + expf(-a));
    }
}

extern "C" void kernel_launch(void* const* d_in, const int* in_sizes, int n_in,
                              void* d_out, int out_size, void* d_ws, size_t ws_size,
                              hipStream_t stream) {
    const float* x     = (const float*)d_in[0];
    const int*   ei    = (const int*)d_in[1];
    const int*   batch = (const int*)d_in[2];
    const float* W1 = (const float*)d_in[3];
    const float* b1 = (const float*)d_in[4];
    const float* g1 = (const float*)d_in[5];
    const float* be1 = (const float*)d_in[6];
    const float* rm1 = (const float*)d_in[7];
    const float* rv1 = (const float*)d_in[8];
    const float* W2 = (const float*)d_in[9];
    const float* b2 = (const float*)d_in[10];
    const float* g2 = (const float*)d_in[11];
    const float* be2 = (const float*)d_in[12];
    const float* rm2 = (const float*)d_in[13];
    const float* rv2 = (const float*)d_in[14];
    const float* W3 = (const float*)d_in[15];
    const float* b3 = (const float*)d_in[16];
    const float* g3 = (const float*)d_in[17];
    const float* be3 = (const float*)d_in[18];
    const float* rm3 = (const float*)d_in[19];
    const float* rv3 = (const float*)d_in[20];
    const float* Wf1 = (const float*)d_in[21];
    const float* bf1 = (const float*)d_in[22];
    const float* Wf2 = (const float*)d_in[23];
    const float* bf2 = (const float*)d_in[24];
    float* out = (float*)d_out;

    const int N = in_sizes[2];            // 100000
    const int E = in_sizes[1] / 2;        // 3200000
    const int G = out_size / 2;           // 256
    const int B = (N + BKN - 1) / BKN;    // buckets (196)

    char* ws = (char*)d_ws;
    size_t off = 0;
    auto alloc = [&](size_t bytes) {
        char* p = ws + off;
        off += (bytes + 255) & ~(size_t)255;
        return p;
    };
    float*          H3     = (float*)alloc((size_t)N * HF * sizeof(float));
    unsigned char*  HS1    = (unsigned char*)alloc((size_t)N * HF);
    unsigned char*  HS2    = (unsigned char*)alloc((size_t)N * HF);
    float*          xs     = (float*)alloc((size_t)N * 5 * sizeof(float));
    float*          dinv   = (float*)alloc((size_t)N * sizeof(float));
    int*            base   = (int*)  alloc(((size_t)N + 1) * sizeof(int));
    int*            bcnt   = (int*)  alloc((size_t)NBUCK_MAX * sizeof(int));
    int*            bbase2 = (int*)  alloc(((size_t)NBUCK_MAX + 1) * sizeof(int));
    int*            bcur   = (int*)  alloc((size_t)NBUCK_MAX * sizeof(int));
    int*            csr    = (int*)  alloc(((size_t)E + 64) * sizeof(int));  // +64 over-read slack
    unsigned short* wf2    = (unsigned short*)alloc(4096 * sizeof(unsigned short));
    unsigned short* wf3    = (unsigned short*)alloc(4096 * sizeof(unsigned short));
    float*          bia2   = (float*)alloc(HF * sizeof(float));
    float*          bia3   = (float*)alloc(HF * sizeof(float));
    int*            stage  = (int*)H3;   // alias: consumed (passC) before H3 written (layer 3)

    const int* src = ei;
    const int* dst = ei + E;

    const int BT = 256;
    int gP  = (N * 5 + BT - 1) / BT;
    int gPB = (E + PB_TILE - 1) / PB_TILE;

    // ---- weight prep (fold BN, bf16, fragment order) ----
    k_prep<<<1, 256, 0, stream>>>(W2, b2, g2, be2, rm2, rv2, wf2, bia2);
    k_prep<<<1, 256, 0, stream>>>(W3, b3, g3, be3, rm3, rv3, wf3, bia3);

    // ---- CSR build ----
    hipMemsetAsync(bcnt, 0, (size_t)B * sizeof(int), stream);
    k_bhist<<<gPB, PB_T, 0, stream>>>(dst, bcnt, E, B);
    k_bscan<<<1, 64, 0, stream>>>(bcnt, bbase2, bcur, base, B, N, E);
    k_passB<<<gPB, PB_T, 0, stream>>>(src, dst, bcur, stage, E, B);
    k_passC<<<B, 512, 0, stream>>>(stage, bbase2, base, dinv, csr, N);
    k_prescale<<<gP, BT, 0, stream>>>(x, dinv, xs, N * 5);

    // ---- fused layers ----
    k_layer1<<<LGRID, BT, 0, stream>>>(xs, HS1, csr, base, dinv,
                                       W1, b1, g1, be1, rm1, rv1, N);
    k_layer<1><<<LGRID, BT, 0, stream>>>(HS1, HS2, csr, base, dinv, wf2, bia2, N);
    k_layer<0><<<LGRID, BT, 0, stream>>>(HS2, H3, csr, base, dinv, wf3, bia3, N);

    // ---- pool + MLP head ----
    k_pool_fc<<<G, BT, 0, stream>>>(H3, batch, Wf1, bf1, Wf2, bf2, out, N);
}